// Round 4
// baseline (1746.877 us; speedup 1.0000x reference)
//
#include <hip/hip_runtime.h>
#include <math.h>

// GTG replicator dynamics. Round 4: iteration GEMM reads A-fragments DIRECTLY
// from global, coalesced via A's symmetry (A[k][m] == A[m][k]) - zero LDS,
// zero barriers. Split-bf16 3-product MFMA everywhere (~fp32 precision).
//
// ws layout (floats):
//   region0 @ 0: nep packed uint [4096][1024] during syrk; afterwards
//     X    [4096][128] f32   @ 0
//     Xth  [128][4096] bf16  @ 524288
//     Xtl  [128][4096] bf16  @ 786432
//   A    [4096][4096] @ 4194304   fp32 from syrk, then packed (hi16|lo16) in place
//   Yp   [skn][4096][128] @ 20971520   (skn = 8 or 16 chosen from ws_size)
//   misc @ 20971520 + skn*524288

#define BSZ  4096
#define DIM  1024
#define NC   100
#define NCP  128
#define NLAB 2048
#define TIT  30

typedef short short8 __attribute__((ext_vector_type(8)));
typedef float f32x16 __attribute__((ext_vector_type(16)));
typedef uint  u32x4  __attribute__((ext_vector_type(4)));

__device__ __forceinline__ float wave_sum(float v) {
#pragma unroll
  for (int off = 32; off > 0; off >>= 1) v += __shfl_xor(v, off, 64);
  return v;
}

__device__ __forceinline__ ushort f2bf(float f) {  // RN float->bf16 bits
  uint u = __float_as_uint(f);
  return (ushort)((u + 0x7fffu + ((u >> 16) & 1u)) >> 16);
}
__device__ __forceinline__ float bf2f(ushort h) {
  return __uint_as_float(((uint)h) << 16);
}
__device__ __forceinline__ uint packsplit(float a) {
  ushort hi = f2bf(a);
  ushort lo = f2bf(a - bf2f(hi));
  return ((uint)hi << 16) | (uint)lo;
}

__device__ __forceinline__ void glds16(const void* g, void* l) {
  __builtin_amdgcn_global_load_lds((const __attribute__((address_space(1))) void*)g,
                                   (__attribute__((address_space(3))) void*)l, 16, 0, 0);
}

// unpack 8 packed uints (2x u32x4, k-ascending) -> hi-frag / lo-frag
__device__ __forceinline__ void unpack8(u32x4 u0, u32x4 u1, short8& h, short8& l) {
  u32x4 hw, lw;
  hw.x = __builtin_amdgcn_perm(u0.y, u0.x, 0x07060302u);
  hw.y = __builtin_amdgcn_perm(u0.w, u0.z, 0x07060302u);
  hw.z = __builtin_amdgcn_perm(u1.y, u1.x, 0x07060302u);
  hw.w = __builtin_amdgcn_perm(u1.w, u1.z, 0x07060302u);
  lw.x = __builtin_amdgcn_perm(u0.y, u0.x, 0x05040100u);
  lw.y = __builtin_amdgcn_perm(u0.w, u0.z, 0x05040100u);
  lw.z = __builtin_amdgcn_perm(u1.y, u1.x, 0x05040100u);
  lw.w = __builtin_amdgcn_perm(u1.w, u1.z, 0x05040100u);
  h = __builtin_bit_cast(short8, hw);
  l = __builtin_bit_cast(short8, lw);
}

// ---- detect label dtype (int32 vs int64 layout) + zero mean acc ----
__global__ void k_detect(const int* __restrict__ lab, double* macc, int* flag) {
  __shared__ int bad;
  if (threadIdx.x == 0) bad = 0;
  __syncthreads();
  int my = 0;
  for (int i = threadIdx.x; i < 1024; i += 256) {
    int lo = lab[2 * i], hi = lab[2 * i + 1];
    if (hi != 0 || lo < 0 || lo >= NC) my = 1;
  }
  if (my) bad = 1;
  __syncthreads();
  if (threadIdx.x == 0) { *macc = 0.0; *flag = (bad ? 0 : 1); }
}

// ---- X0 ----
__global__ void k_init_x(const int* __restrict__ lab, const int* __restrict__ flag,
                         float* __restrict__ X) {
  int gid = blockIdx.x * 256 + threadIdx.x;
  if (gid >= BSZ * (NCP / 4)) return;
  int i = gid >> 5, c4 = (gid & 31) << 2;
  float4 v;
  if (i < NLAB) {
    int l = (*flag) ? lab[2 * i] : lab[i];
    v.x = (c4 + 0 == l) ? 1.f : 0.f;
    v.y = (c4 + 1 == l) ? 1.f : 0.f;
    v.z = (c4 + 2 == l) ? 1.f : 0.f;
    v.w = (c4 + 3 == l) ? 1.f : 0.f;
  } else {
    v.x = (c4 + 0 < NC) ? 0.01f : 0.f;
    v.y = (c4 + 1 < NC) ? 0.01f : 0.f;
    v.z = (c4 + 2 < NC) ? 0.01f : 0.f;
    v.w = (c4 + 3 < NC) ? 0.01f : 0.f;
  }
  *(float4*)(X + (size_t)i * NCP + c4) = v;
}

// ---- row-normalize embedding -> packed split-bf16 ne ----
__global__ __launch_bounds__(256) void k_normalize(const float* __restrict__ emb,
                                                   uint* __restrict__ nep) {
  int row = blockIdx.x, t = threadIdx.x;
  float4 v = ((const float4*)(emb + (size_t)row * DIM))[t];
  float ss = v.x * v.x + v.y * v.y + v.z * v.z + v.w * v.w;
  ss = wave_sum(ss);
  __shared__ float red[4];
  int lane = t & 63, wid = t >> 6;
  if (lane == 0) red[wid] = ss;
  __syncthreads();
  float tot = red[0] + red[1] + red[2] + red[3];
  float sc = 1.0f / (sqrtf(tot) + 1e-12f);
  uint4 o;
  o.x = packsplit(v.x * sc);
  o.y = packsplit(v.y * sc);
  o.z = packsplit(v.z * sc);
  o.w = packsplit(v.w * sc);
  ((uint4*)(nep + (size_t)row * DIM))[t] = o;
}

// ---- A = ne*ne^T via split-bf16 MFMA; clamp[0,1], diag=0, mean acc ----
__global__ __launch_bounds__(256) void k_syrk(const uint* __restrict__ nep,
                                              float* __restrict__ A,
                                              double* __restrict__ macc) {
  int p = blockIdx.x;
  int bi = 0, rem = p;
  while (rem >= 32 - bi) { rem -= 32 - bi; bi++; }
  int bj = bi + rem;
  int rb = bi << 7, cb = bj << 7;

  __shared__ uint sP[2][2][4096];
  __shared__ float red[4];

  int t = threadIdx.x, lane = t & 63, wid = t >> 6;
  int wm = wid >> 1, wn = wid & 1;
  int l31 = lane & 31, lh = lane >> 5;

  f32x16 acc[2][2];
#pragma unroll
  for (int mi = 0; mi < 2; mi++)
#pragma unroll
    for (int ni = 0; ni < 2; ni++)
#pragma unroll
      for (int r = 0; r < 16; r++) acc[mi][ni][r] = 0.f;

#define SYRK_STAGE(BUF, K0) {                                                  \
    int base0 = rb, base1 = cb;                                                \
    _Pragma("unroll")                                                          \
    for (int i = 0; i < 4; i++) {                                              \
      int s = wid * 256 + i * 64 + lane;                                       \
      int row = s >> 3;                                                        \
      int g = (s & 7) ^ (row & 7);                                             \
      glds16(nep + (size_t)(base0 + row) * DIM + (K0) + g * 4,                 \
             &sP[BUF][0][(wid * 256 + i * 64) * 4]);                           \
      glds16(nep + (size_t)(base1 + row) * DIM + (K0) + g * 4,                 \
             &sP[BUF][1][(wid * 256 + i * 64) * 4]);                           \
    }                                                                          \
  }

  SYRK_STAGE(0, 0);
  __syncthreads();
  for (int kt = 0; kt < 32; kt++) {
    int cur = kt & 1;
    if (kt + 1 < 32) SYRK_STAGE(cur ^ 1, (kt + 1) * 32);
#pragma unroll
    for (int ks = 0; ks < 2; ks++) {
      int g0 = ks * 4 + lh * 2;
      short8 ah[2], al[2], bh[2], bl[2];
#pragma unroll
      for (int mi = 0; mi < 2; mi++) {
        int row = wm * 64 + mi * 32 + l31;
        const uint* pb = &sP[cur][0][0];
        u32x4 u0 = *(const u32x4*)(pb + ((row << 3) + (g0 ^ (row & 7))) * 4);
        u32x4 u1 = *(const u32x4*)(pb + ((row << 3) + ((g0 + 1) ^ (row & 7))) * 4);
        unpack8(u0, u1, ah[mi], al[mi]);
      }
#pragma unroll
      for (int ni = 0; ni < 2; ni++) {
        int row = wn * 64 + ni * 32 + l31;
        const uint* pb = &sP[cur][1][0];
        u32x4 u0 = *(const u32x4*)(pb + ((row << 3) + (g0 ^ (row & 7))) * 4);
        u32x4 u1 = *(const u32x4*)(pb + ((row << 3) + ((g0 + 1) ^ (row & 7))) * 4);
        unpack8(u0, u1, bh[ni], bl[ni]);
      }
#pragma unroll
      for (int mi = 0; mi < 2; mi++)
#pragma unroll
        for (int ni = 0; ni < 2; ni++) {
          acc[mi][ni] = __builtin_amdgcn_mfma_f32_32x32x16_bf16(ah[mi], bh[ni], acc[mi][ni], 0, 0, 0);
          acc[mi][ni] = __builtin_amdgcn_mfma_f32_32x32x16_bf16(ah[mi], bl[ni], acc[mi][ni], 0, 0, 0);
          acc[mi][ni] = __builtin_amdgcn_mfma_f32_32x32x16_bf16(al[mi], bh[ni], acc[mi][ni], 0, 0, 0);
        }
    }
    __syncthreads();
  }

  float lsum = 0.f;
#pragma unroll
  for (int mi = 0; mi < 2; mi++)
#pragma unroll
    for (int ni = 0; ni < 2; ni++)
#pragma unroll
      for (int r = 0; r < 16; r++) {
        int gr = rb + wm * 64 + mi * 32 + (r & 3) + 8 * (r >> 2) + 4 * lh;
        int gc = cb + wn * 64 + ni * 32 + l31;
        float v = acc[mi][ni][r];
        v = fminf(fmaxf(v, 0.f), 1.f);
        if (gr == gc) v = 0.f;
        acc[mi][ni][r] = v;
        lsum += v;
        A[(size_t)gr * BSZ + gc] = v;
      }
  if (bi != bj) lsum *= 2.f;
  float bs = wave_sum(lsum);
  if (lane == 0) red[wid] = bs;
  __syncthreads();
  if (t == 0) atomicAdd(macc, (double)(red[0] + red[1] + red[2] + red[3]));

  if (bi != bj) {
    float* tb = (float*)&sP[0][0][0];
#pragma unroll
    for (int ph2 = 0; ph2 < 2; ph2++) {
      __syncthreads();
      if (wm == ph2) {
#pragma unroll
        for (int mi = 0; mi < 2; mi++)
#pragma unroll
          for (int ni = 0; ni < 2; ni++)
#pragma unroll
            for (int r = 0; r < 16; r++) {
              int rl = mi * 32 + (r & 3) + 8 * (r >> 2) + 4 * lh;
              int cl = wn * 64 + ni * 32 + l31;
              tb[rl * 132 + cl] = acc[mi][ni][r];
            }
      }
      __syncthreads();
      int col = t >> 1, rh = (t & 1) * 32;
      float* dst = A + (size_t)(cb + col) * BSZ + rb + ph2 * 64 + rh;
#pragma unroll
      for (int q = 0; q < 8; q++) {
        float4 v4 = make_float4(tb[(rh + q * 4 + 0) * 132 + col],
                                tb[(rh + q * 4 + 1) * 132 + col],
                                tb[(rh + q * 4 + 2) * 132 + col],
                                tb[(rh + q * 4 + 3) * 132 + col]);
        *(float4*)(dst + q * 4) = v4;
      }
    }
  }
}

__global__ void k_meanfin(const double* __restrict__ macc, float* __restrict__ meanf) {
  *meanf = (float)(*macc / (double)((long long)BSZ * BSZ));
}

// ---- threshold + split-bf16 + pack A in place ----
__global__ __launch_bounds__(256) void k_split_a(float* __restrict__ A,
                                                 const float* __restrict__ meanf) {
  float mean = *meanf;
  int b = blockIdx.x, t = threadIdx.x;
#pragma unroll
  for (int i = 0; i < 8; i++) {
    size_t idx = ((size_t)i * 2048 * 256 + (size_t)b * 256 + t);
    float4 v = *(const float4*)(A + idx * 4);
    uint4 o;
    o.x = packsplit((v.x < mean) ? 0.f : v.x);
    o.y = packsplit((v.y < mean) ? 0.f : v.y);
    o.z = packsplit((v.z < mean) ? 0.f : v.z);
    o.w = packsplit((v.w < mean) ? 0.f : v.w);
    *(uint4*)(A + idx * 4) = o;
  }
}

// ---- initial X split+transpose ----
__global__ __launch_bounds__(256) void k_splitx0(const float* __restrict__ X,
                                                 ushort* __restrict__ Xth,
                                                 ushort* __restrict__ Xtl) {
  __shared__ float xk[64][132];
  int t = threadIdx.x;
  int k0 = blockIdx.x * 64;
#pragma unroll
  for (int p = 0; p < 8; p++) {
    int v = p * 256 + t;
    int krow = v >> 5, q = v & 31;
    float4 f = *(const float4*)(X + (size_t)(k0 + krow) * NCP + q * 4);
    *(float4*)&xk[krow][q * 4] = f;
  }
  __syncthreads();
  int n = t >> 1, half = t & 1;
  ushort hh[32], ll[32];
#pragma unroll
  for (int j = 0; j < 32; j++) {
    float v = xk[half * 32 + j][n];
    ushort hi = f2bf(v);
    hh[j] = hi;
    ll[j] = f2bf(v - bf2f(hi));
  }
  size_t base = (size_t)n * BSZ + k0 + half * 32;
#pragma unroll
  for (int g = 0; g < 4; g++) {
    uint4 oh, ol;
    oh.x = (uint)hh[g*8+0] | ((uint)hh[g*8+1] << 16);
    oh.y = (uint)hh[g*8+2] | ((uint)hh[g*8+3] << 16);
    oh.z = (uint)hh[g*8+4] | ((uint)hh[g*8+5] << 16);
    oh.w = (uint)hh[g*8+6] | ((uint)hh[g*8+7] << 16);
    ol.x = (uint)ll[g*8+0] | ((uint)ll[g*8+1] << 16);
    ol.y = (uint)ll[g*8+2] | ((uint)ll[g*8+3] << 16);
    ol.z = (uint)ll[g*8+4] | ((uint)ll[g*8+5] << 16);
    ol.w = (uint)ll[g*8+6] | ((uint)ll[g*8+7] << 16);
    *(uint4*)(Xth + base + g * 8) = oh;
    *(uint4*)(Xtl + base + g * 8) = ol;
  }
}

// ---- MFMA GEMM, direct-global fragments (A symmetric -> A[k][m] coalesced).
// No LDS, no barriers. 2-phase register pipeline, 3-product split-bf16. ----
__global__ __launch_bounds__(256) void k_gemm(const uint* __restrict__ Ap,
                                              const ushort* __restrict__ Xth,
                                              const ushort* __restrict__ Xtl,
                                              float* __restrict__ Yp,
                                              int kcw) {
  int b = blockIdx.x;
  int mt = b & 31, sk = b >> 5;
  int rbase = mt << 7;
  int kc0 = sk * kcw;
  int nks = kcw >> 4;

  int t = threadIdx.x, lane = t & 63, wid = t >> 6;
  int wm = wid >> 1, wn = wid & 1;
  int l31 = lane & 31, lh = lane >> 5;

  int m0 = rbase + wm * 64 + l31;   // +32 for mi=1
  int c0 = wn * 64 + l31;           // +32 for ni=1

  f32x16 acc[2][2];
#pragma unroll
  for (int mi = 0; mi < 2; mi++)
#pragma unroll
    for (int ni = 0; ni < 2; ni++)
#pragma unroll
      for (int r = 0; r < 16; r++) acc[mi][ni][r] = 0.f;

#define LOADK(KS, A0, A1, BH0, BL0, BH1, BL1) {                                \
    int kk = kc0 + (KS) * 16 + lh * 8;                                         \
    const uint* ap = Ap + (size_t)kk * BSZ + m0;                               \
    _Pragma("unroll")                                                          \
    for (int j = 0; j < 8; j++) {                                              \
      A0[j] = ap[(size_t)j * BSZ];                                             \
      A1[j] = ap[(size_t)j * BSZ + 32];                                        \
    }                                                                          \
    BH0 = *(const short8*)(Xth + (size_t)c0 * BSZ + kk);                       \
    BL0 = *(const short8*)(Xtl + (size_t)c0 * BSZ + kk);                       \
    BH1 = *(const short8*)(Xth + (size_t)(c0 + 32) * BSZ + kk);                \
    BL1 = *(const short8*)(Xtl + (size_t)(c0 + 32) * BSZ + kk);                \
  }

#define COMPUTE(A0, A1, BH0, BL0, BH1, BL1) {                                  \
    u32x4 u0, u1;                                                              \
    short8 ah, al;                                                             \
    u0.x = A0[0]; u0.y = A0[1]; u0.z = A0[2]; u0.w = A0[3];                    \
    u1.x = A0[4]; u1.y = A0[5]; u1.z = A0[6]; u1.w = A0[7];                    \
    unpack8(u0, u1, ah, al);                                                   \
    acc[0][0] = __builtin_amdgcn_mfma_f32_32x32x16_bf16(ah, BH0, acc[0][0], 0, 0, 0); \
    acc[0][0] = __builtin_amdgcn_mfma_f32_32x32x16_bf16(ah, BL0, acc[0][0], 0, 0, 0); \
    acc[0][0] = __builtin_amdgcn_mfma_f32_32x32x16_bf16(al, BH0, acc[0][0], 0, 0, 0); \
    acc[0][1] = __builtin_amdgcn_mfma_f32_32x32x16_bf16(ah, BH1, acc[0][1], 0, 0, 0); \
    acc[0][1] = __builtin_amdgcn_mfma_f32_32x32x16_bf16(ah, BL1, acc[0][1], 0, 0, 0); \
    acc[0][1] = __builtin_amdgcn_mfma_f32_32x32x16_bf16(al, BH1, acc[0][1], 0, 0, 0); \
    u0.x = A1[0]; u0.y = A1[1]; u0.z = A1[2]; u0.w = A1[3];                    \
    u1.x = A1[4]; u1.y = A1[5]; u1.z = A1[6]; u1.w = A1[7];                    \
    unpack8(u0, u1, ah, al);                                                   \
    acc[1][0] = __builtin_amdgcn_mfma_f32_32x32x16_bf16(ah, BH0, acc[1][0], 0, 0, 0); \
    acc[1][0] = __builtin_amdgcn_mfma_f32_32x32x16_bf16(ah, BL0, acc[1][0], 0, 0, 0); \
    acc[1][0] = __builtin_amdgcn_mfma_f32_32x32x16_bf16(al, BH0, acc[1][0], 0, 0, 0); \
    acc[1][1] = __builtin_amdgcn_mfma_f32_32x32x16_bf16(ah, BH1, acc[1][1], 0, 0, 0); \
    acc[1][1] = __builtin_amdgcn_mfma_f32_32x32x16_bf16(ah, BL1, acc[1][1], 0, 0, 0); \
    acc[1][1] = __builtin_amdgcn_mfma_f32_32x32x16_bf16(al, BH1, acc[1][1], 0, 0, 0); \
  }

  uint a0A[8], a1A[8], a0B[8], a1B[8];
  short8 bh0A, bl0A, bh1A, bl1A, bh0B, bl0B, bh1B, bl1B;

  LOADK(0, a0A, a1A, bh0A, bl0A, bh1A, bl1A);
  for (int ks = 0; ks < nks; ks += 2) {
    LOADK(ks + 1, a0B, a1B, bh0B, bl0B, bh1B, bl1B);
    COMPUTE(a0A, a1A, bh0A, bl0A, bh1A, bl1A);
    if (ks + 2 < nks) LOADK(ks + 2, a0A, a1A, bh0A, bl0A, bh1A, bl1A);
    COMPUTE(a0B, a1B, bh0B, bl0B, bh1B, bl1B);
  }

  float* yb = Yp + (size_t)sk * (BSZ * NCP);
#pragma unroll
  for (int mi = 0; mi < 2; mi++)
#pragma unroll
    for (int ni = 0; ni < 2; ni++)
#pragma unroll
      for (int r = 0; r < 16; r++) {
        int row = rbase + wm * 64 + mi * 32 + (r & 3) + 8 * (r >> 2) + 4 * lh;
        int col = wn * 64 + ni * 32 + l31;
        yb[(size_t)row * NCP + col] = acc[mi][ni][r];
      }
}

// ---- epilogue: sum partials, div, entropy, X+=div, outputs, X split+transpose ----
__global__ __launch_bounds__(256) void k_epilogue2(const float* __restrict__ Yp,
                                                   float* __restrict__ X,
                                                   float* __restrict__ out,
                                                   ushort* __restrict__ Xth,
                                                   ushort* __restrict__ Xtl,
                                                   int tit, int skn) {
  __shared__ float xn[16][132];
  int t = threadIdx.x;
  int lane = t & 63, w = t >> 6;
  int r0 = blockIdx.x * 16;
  int c0 = lane << 1;
#pragma unroll
  for (int rr = 0; rr < 4; rr++) {
    int row = r0 + w * 4 + rr;
    float y0 = 0.f, y1 = 0.f;
    for (int sk = 0; sk < skn; sk++) {
      float2 v = *(const float2*)(Yp + (size_t)sk * BSZ * NCP + (size_t)row * NCP + c0);
      y0 += v.x; y1 += v.y;
    }
    float2 xv = *(float2*)(X + (size_t)row * NCP + c0);
    float n0 = xv.x * y0, n1 = xv.y * y1;
    float s = wave_sum(n0 + n1);
    float inv = 1.0f / (s + 1e-8f);
    float d0 = n0 * inv, d1 = n1 * inv;
    float e = -(d0 * logf(d0 + 1e-20f)) - (d1 * logf(d1 + 1e-20f));
    e = wave_sum(e);
    float nx0 = xv.x + d0, nx1 = xv.y + d1;
    xv.x = nx0; xv.y = nx1;
    *(float2*)(X + (size_t)row * NCP + c0) = xv;
    xn[w * 4 + rr][c0] = nx0;
    xn[w * 4 + rr][c0 + 1] = nx1;
    if (c0 < NC)     out[((size_t)row * NC + c0) * TIT + tit] = d0;
    if (c0 + 1 < NC) out[((size_t)row * NC + c0 + 1) * TIT + tit] = d1;
    if (lane == 0)   out[(size_t)BSZ * NC * TIT + (size_t)row * TIT + tit] = e;
  }
  __syncthreads();
  int n = t & 127, half = t >> 7;
  ushort hh[8], ll[8];
#pragma unroll
  for (int j = 0; j < 8; j++) {
    float v = xn[half * 8 + j][n];
    ushort hi = f2bf(v);
    hh[j] = hi;
    ll[j] = f2bf(v - bf2f(hi));
  }
  size_t bofs = (size_t)n * BSZ + r0 + half * 8;
  uint4 oh, ol;
  oh.x = (uint)hh[0] | ((uint)hh[1] << 16);
  oh.y = (uint)hh[2] | ((uint)hh[3] << 16);
  oh.z = (uint)hh[4] | ((uint)hh[5] << 16);
  oh.w = (uint)hh[6] | ((uint)hh[7] << 16);
  ol.x = (uint)ll[0] | ((uint)ll[1] << 16);
  ol.y = (uint)ll[2] | ((uint)ll[3] << 16);
  ol.z = (uint)ll[4] | ((uint)ll[5] << 16);
  ol.w = (uint)ll[6] | ((uint)ll[7] << 16);
  *(uint4*)(Xth + bofs) = oh;
  *(uint4*)(Xtl + bofs) = ol;
}

extern "C" void kernel_launch(void* const* d_in, const int* in_sizes, int n_in,
                              void* d_out, int out_size, void* d_ws, size_t ws_size,
                              hipStream_t stream) {
  const float* emb = (const float*)d_in[0];
  const int* lab = (const int*)d_in[1];
  float* out = (float*)d_out;
  float* ws = (float*)d_ws;

  uint*   nep = (uint*)ws;                       // region0, dead after syrk
  float*  X   = ws;                              // aliases nep (post-syrk)
  ushort* Xth = (ushort*)(ws + 524288);
  ushort* Xtl = (ushort*)(ws + 524288 + 262144);
  float*  A   = ws + 4194304;                    // fp32, then packed in place
  uint*   Ap  = (uint*)A;
  float*  Yp  = ws + 20971520;

  size_t need16 = ((size_t)20971520 + 16 * 524288 + 16) * 4;
  int skn = (ws_size >= need16) ? 16 : 8;
  int kcw = BSZ / skn;

  float* misc = ws + 20971520 + (size_t)skn * 524288;
  double* macc = (double*)misc;
  float* meanf = misc + 2;
  int* flag = (int*)(misc + 3);

  k_detect<<<dim3(1), dim3(256), 0, stream>>>(lab, macc, flag);
  k_normalize<<<dim3(BSZ), dim3(256), 0, stream>>>(emb, nep);
  k_syrk<<<dim3(528), dim3(256), 0, stream>>>(nep, A, macc);
  k_meanfin<<<dim3(1), dim3(1), 0, stream>>>(macc, meanf);
  k_split_a<<<dim3(2048), dim3(256), 0, stream>>>(A, meanf);
  k_init_x<<<dim3((BSZ * (NCP / 4) + 255) / 256), dim3(256), 0, stream>>>(lab, flag, X);
  k_splitx0<<<dim3(64), dim3(256), 0, stream>>>(X, Xth, Xtl);
  for (int t = 0; t < TIT; t++) {
    k_gemm<<<dim3(32 * skn), dim3(256), 0, stream>>>(Ap, Xth, Xtl, Yp, kcw);
    k_epilogue2<<<dim3(256), dim3(256), 0, stream>>>(Yp, X, out, Xth, Xtl, t, skn);
  }
}

// Round 5
// 1482.195 us; speedup vs baseline: 1.1786x; 1.1786x over previous
//
#include <hip/hip_runtime.h>
#include <math.h>

// GTG replicator dynamics. Round 5: fragment-major A/X layouts so the
// iteration GEMM reads MFMA fragments as coalesced dwordx4 streams straight
// from global (no LDS, no barriers). Split-bf16 3-product MFMA (~fp32).
//
// Layouts:
//   Af32/Apf [kt=256][m=4096][sub=16]  (kt=k/16, sub=k%15): fp32 from syrk,
//       packed (hi16|lo16) in place by elementwise k_split_a.
//   Xthf/Xtlf [kt=256][n=128][sub=16] bf16 fragment-major.
//
// ws layout (floats):
//   region0 @ 0: X [4096][128] f32 @ 0; Xthf @ 524288; Xtlf @ 786432
//   A    [kt][m][sub] @ 4194304  (67 MB)
//   Yp   [skn][4096][128] @ 20971520
//   misc @ 20971520 + skn*524288

#define BSZ  4096
#define DIM  1024
#define NC   100
#define NCP  128
#define NLAB 2048
#define TIT  30

typedef short short8 __attribute__((ext_vector_type(8)));
typedef float f32x16 __attribute__((ext_vector_type(16)));
typedef uint  u32x4  __attribute__((ext_vector_type(4)));

__device__ __forceinline__ float wave_sum(float v) {
#pragma unroll
  for (int off = 32; off > 0; off >>= 1) v += __shfl_xor(v, off, 64);
  return v;
}

__device__ __forceinline__ ushort f2bf(float f) {  // RN float->bf16 bits
  uint u = __float_as_uint(f);
  return (ushort)((u + 0x7fffu + ((u >> 16) & 1u)) >> 16);
}
__device__ __forceinline__ float bf2f(ushort h) {
  return __uint_as_float(((uint)h) << 16);
}
__device__ __forceinline__ uint packsplit(float a) {
  ushort hi = f2bf(a);
  ushort lo = f2bf(a - bf2f(hi));
  return ((uint)hi << 16) | (uint)lo;
}

__device__ __forceinline__ void glds16(const void* g, void* l) {
  __builtin_amdgcn_global_load_lds((const __attribute__((address_space(1))) void*)g,
                                   (__attribute__((address_space(3))) void*)l, 16, 0, 0);
}

// unpack 8 packed uints (2x u32x4, k-ascending) -> hi-frag / lo-frag
__device__ __forceinline__ void unpack8(u32x4 u0, u32x4 u1, short8& h, short8& l) {
  u32x4 hw, lw;
  hw.x = __builtin_amdgcn_perm(u0.y, u0.x, 0x07060302u);
  hw.y = __builtin_amdgcn_perm(u0.w, u0.z, 0x07060302u);
  hw.z = __builtin_amdgcn_perm(u1.y, u1.x, 0x07060302u);
  hw.w = __builtin_amdgcn_perm(u1.w, u1.z, 0x07060302u);
  lw.x = __builtin_amdgcn_perm(u0.y, u0.x, 0x05040100u);
  lw.y = __builtin_amdgcn_perm(u0.w, u0.z, 0x05040100u);
  lw.z = __builtin_amdgcn_perm(u1.y, u1.x, 0x05040100u);
  lw.w = __builtin_amdgcn_perm(u1.w, u1.z, 0x05040100u);
  h = __builtin_bit_cast(short8, hw);
  l = __builtin_bit_cast(short8, lw);
}

// ---- detect label dtype (int32 vs int64 layout) + zero mean acc ----
__global__ void k_detect(const int* __restrict__ lab, double* macc, int* flag) {
  __shared__ int bad;
  if (threadIdx.x == 0) bad = 0;
  __syncthreads();
  int my = 0;
  for (int i = threadIdx.x; i < 1024; i += 256) {
    int lo = lab[2 * i], hi = lab[2 * i + 1];
    if (hi != 0 || lo < 0 || lo >= NC) my = 1;
  }
  if (my) bad = 1;
  __syncthreads();
  if (threadIdx.x == 0) { *macc = 0.0; *flag = (bad ? 0 : 1); }
}

// ---- X0 ----
__global__ void k_init_x(const int* __restrict__ lab, const int* __restrict__ flag,
                         float* __restrict__ X) {
  int gid = blockIdx.x * 256 + threadIdx.x;
  if (gid >= BSZ * (NCP / 4)) return;
  int i = gid >> 5, c4 = (gid & 31) << 2;
  float4 v;
  if (i < NLAB) {
    int l = (*flag) ? lab[2 * i] : lab[i];
    v.x = (c4 + 0 == l) ? 1.f : 0.f;
    v.y = (c4 + 1 == l) ? 1.f : 0.f;
    v.z = (c4 + 2 == l) ? 1.f : 0.f;
    v.w = (c4 + 3 == l) ? 1.f : 0.f;
  } else {
    v.x = (c4 + 0 < NC) ? 0.01f : 0.f;
    v.y = (c4 + 1 < NC) ? 0.01f : 0.f;
    v.z = (c4 + 2 < NC) ? 0.01f : 0.f;
    v.w = (c4 + 3 < NC) ? 0.01f : 0.f;
  }
  *(float4*)(X + (size_t)i * NCP + c4) = v;
}

// ---- row-normalize embedding -> packed split-bf16 ne ----
__global__ __launch_bounds__(256) void k_normalize(const float* __restrict__ emb,
                                                   uint* __restrict__ nep) {
  int row = blockIdx.x, t = threadIdx.x;
  float4 v = ((const float4*)(emb + (size_t)row * DIM))[t];
  float ss = v.x * v.x + v.y * v.y + v.z * v.z + v.w * v.w;
  ss = wave_sum(ss);
  __shared__ float red[4];
  int lane = t & 63, wid = t >> 6;
  if (lane == 0) red[wid] = ss;
  __syncthreads();
  float tot = red[0] + red[1] + red[2] + red[3];
  float sc = 1.0f / (sqrtf(tot) + 1e-12f);
  uint4 o;
  o.x = packsplit(v.x * sc);
  o.y = packsplit(v.y * sc);
  o.z = packsplit(v.z * sc);
  o.w = packsplit(v.w * sc);
  ((uint4*)(nep + (size_t)row * DIM))[t] = o;
}

// ---- A = ne*ne^T via split-bf16 MFMA; clamp[0,1], diag=0, mean acc.
// Stores fragment-major fp32: Af[kt=gc>>4][m=gr][sub=gc&15]. ----
__global__ __launch_bounds__(256) void k_syrk(const uint* __restrict__ nep,
                                              float* __restrict__ Af,
                                              double* __restrict__ macc) {
  int p = blockIdx.x;
  int bi = 0, rem = p;
  while (rem >= 32 - bi) { rem -= 32 - bi; bi++; }
  int bj = bi + rem;
  int rb = bi << 7, cb = bj << 7;

  __shared__ uint sP[2][2][4096];
  __shared__ float red[4];

  int t = threadIdx.x, lane = t & 63, wid = t >> 6;
  int wm = wid >> 1, wn = wid & 1;
  int l31 = lane & 31, lh = lane >> 5;

  f32x16 acc[2][2];
#pragma unroll
  for (int mi = 0; mi < 2; mi++)
#pragma unroll
    for (int ni = 0; ni < 2; ni++)
#pragma unroll
      for (int r = 0; r < 16; r++) acc[mi][ni][r] = 0.f;

#define SYRK_STAGE(BUF, K0) {                                                  \
    int base0 = rb, base1 = cb;                                                \
    _Pragma("unroll")                                                          \
    for (int i = 0; i < 4; i++) {                                              \
      int s = wid * 256 + i * 64 + lane;                                       \
      int row = s >> 3;                                                        \
      int g = (s & 7) ^ (row & 7);                                             \
      glds16(nep + (size_t)(base0 + row) * DIM + (K0) + g * 4,                 \
             &sP[BUF][0][(wid * 256 + i * 64) * 4]);                           \
      glds16(nep + (size_t)(base1 + row) * DIM + (K0) + g * 4,                 \
             &sP[BUF][1][(wid * 256 + i * 64) * 4]);                           \
    }                                                                          \
  }

  SYRK_STAGE(0, 0);
  __syncthreads();
  for (int kt = 0; kt < 32; kt++) {
    int cur = kt & 1;
    if (kt + 1 < 32) SYRK_STAGE(cur ^ 1, (kt + 1) * 32);
#pragma unroll
    for (int ks = 0; ks < 2; ks++) {
      int g0 = ks * 4 + lh * 2;
      short8 ah[2], al[2], bh[2], bl[2];
#pragma unroll
      for (int mi = 0; mi < 2; mi++) {
        int row = wm * 64 + mi * 32 + l31;
        const uint* pb = &sP[cur][0][0];
        u32x4 u0 = *(const u32x4*)(pb + ((row << 3) + (g0 ^ (row & 7))) * 4);
        u32x4 u1 = *(const u32x4*)(pb + ((row << 3) + ((g0 + 1) ^ (row & 7))) * 4);
        unpack8(u0, u1, ah[mi], al[mi]);
      }
#pragma unroll
      for (int ni = 0; ni < 2; ni++) {
        int row = wn * 64 + ni * 32 + l31;
        const uint* pb = &sP[cur][1][0];
        u32x4 u0 = *(const u32x4*)(pb + ((row << 3) + (g0 ^ (row & 7))) * 4);
        u32x4 u1 = *(const u32x4*)(pb + ((row << 3) + ((g0 + 1) ^ (row & 7))) * 4);
        unpack8(u0, u1, bh[ni], bl[ni]);
      }
#pragma unroll
      for (int mi = 0; mi < 2; mi++)
#pragma unroll
        for (int ni = 0; ni < 2; ni++) {
          acc[mi][ni] = __builtin_amdgcn_mfma_f32_32x32x16_bf16(ah[mi], bh[ni], acc[mi][ni], 0, 0, 0);
          acc[mi][ni] = __builtin_amdgcn_mfma_f32_32x32x16_bf16(ah[mi], bl[ni], acc[mi][ni], 0, 0, 0);
          acc[mi][ni] = __builtin_amdgcn_mfma_f32_32x32x16_bf16(al[mi], bh[ni], acc[mi][ni], 0, 0, 0);
        }
    }
    __syncthreads();
  }

  // epilogue: clamp, diag, mean; direct fragment-major store (upper tile)
  float lsum = 0.f;
#pragma unroll
  for (int mi = 0; mi < 2; mi++)
#pragma unroll
    for (int ni = 0; ni < 2; ni++)
#pragma unroll
      for (int r = 0; r < 16; r++) {
        int gr = rb + wm * 64 + mi * 32 + (r & 3) + 8 * (r >> 2) + 4 * lh;
        int gc = cb + wn * 64 + ni * 32 + l31;
        float v = acc[mi][ni][r];
        v = fminf(fmaxf(v, 0.f), 1.f);
        if (gr == gc) v = 0.f;
        acc[mi][ni][r] = v;
        lsum += v;
        Af[(size_t)(gc >> 4) * 65536 + ((size_t)gr << 4) + (gc & 15)] = v;
      }
  if (bi != bj) lsum *= 2.f;
  float bs = wave_sum(lsum);
  if (lane == 0) red[wid] = bs;
  __syncthreads();
  if (t == 0) atomicAdd(macc, (double)(red[0] + red[1] + red[2] + red[3]));

  // mirror store A[gc][gr] via LDS transpose, fragment-major addressing
  if (bi != bj) {
    float* tb = (float*)&sP[0][0][0];
#pragma unroll
    for (int ph2 = 0; ph2 < 2; ph2++) {
      __syncthreads();
      if (wm == ph2) {
#pragma unroll
        for (int mi = 0; mi < 2; mi++)
#pragma unroll
          for (int ni = 0; ni < 2; ni++)
#pragma unroll
            for (int r = 0; r < 16; r++) {
              int rl = mi * 32 + (r & 3) + 8 * (r >> 2) + 4 * lh;
              int cl = wn * 64 + ni * 32 + l31;
              tb[rl * 132 + cl] = acc[mi][ni][r];
            }
      }
      __syncthreads();
      int col = t >> 1, rh = (t & 1) * 32;
      int grbase = rb + ph2 * 64 + rh;   // multiple of 32
#pragma unroll
      for (int q = 0; q < 8; q++) {
        int g4 = grbase + q * 4;         // gr of first elem; sub-run of 4
        float4 v4 = make_float4(tb[(rh + q * 4 + 0) * 132 + col],
                                tb[(rh + q * 4 + 1) * 132 + col],
                                tb[(rh + q * 4 + 2) * 132 + col],
                                tb[(rh + q * 4 + 3) * 132 + col]);
        *(float4*)(Af + (size_t)(g4 >> 4) * 65536 + ((size_t)(cb + col) << 4) + (g4 & 15)) = v4;
      }
    }
  }
}

__global__ void k_meanfin(const double* __restrict__ macc, float* __restrict__ meanf) {
  *meanf = (float)(*macc / (double)((long long)BSZ * BSZ));
}

// ---- threshold + split-bf16 + pack, elementwise IN PLACE (layout unchanged) ----
__global__ __launch_bounds__(256) void k_split_a(float* __restrict__ A,
                                                 const float* __restrict__ meanf) {
  float mean = *meanf;
  size_t base = ((size_t)blockIdx.x * 256 + threadIdx.x) * 16;
#pragma unroll
  for (int q = 0; q < 4; q++) {
    float4 v = *(const float4*)(A + base + q * 4);
    uint4 o;
    o.x = packsplit((v.x < mean) ? 0.f : v.x);
    o.y = packsplit((v.y < mean) ? 0.f : v.y);
    o.z = packsplit((v.z < mean) ? 0.f : v.z);
    o.w = packsplit((v.w < mean) ? 0.f : v.w);
    *(uint4*)(A + base + q * 4) = o;
  }
}

// ---- initial X split -> fragment-major Xthf/Xtlf [kt][n][sub] ----
__global__ __launch_bounds__(256) void k_splitx0(const float* __restrict__ X,
                                                 ushort* __restrict__ Xthf,
                                                 ushort* __restrict__ Xtlf) {
  int gid = blockIdx.x * 256 + threadIdx.x;   // 128 blocks -> 32768 threads
  int n = gid & 127, kt = gid >> 7;
  ushort hh[16], ll[16];
#pragma unroll
  for (int j = 0; j < 16; j++) {
    float v = X[(size_t)(kt * 16 + j) * NCP + n];
    ushort hi = f2bf(v);
    hh[j] = hi;
    ll[j] = f2bf(v - bf2f(hi));
  }
  size_t base = ((size_t)kt * NCP + n) * 16;
#pragma unroll
  for (int g = 0; g < 2; g++) {
    uint4 oh, ol;
    oh.x = (uint)hh[g*8+0] | ((uint)hh[g*8+1] << 16);
    oh.y = (uint)hh[g*8+2] | ((uint)hh[g*8+3] << 16);
    oh.z = (uint)hh[g*8+4] | ((uint)hh[g*8+5] << 16);
    oh.w = (uint)hh[g*8+6] | ((uint)hh[g*8+7] << 16);
    ol.x = (uint)ll[g*8+0] | ((uint)ll[g*8+1] << 16);
    ol.y = (uint)ll[g*8+2] | ((uint)ll[g*8+3] << 16);
    ol.z = (uint)ll[g*8+4] | ((uint)ll[g*8+5] << 16);
    ol.w = (uint)ll[g*8+6] | ((uint)ll[g*8+7] << 16);
    *(uint4*)(Xthf + base + g * 8) = oh;
    *(uint4*)(Xtlf + base + g * 8) = ol;
  }
}

// ---- MFMA GEMM, fragment-major direct-global loads: per k-step 8 coalesced
// 16B loads + 12 MFMA. No LDS, no barriers. 2-deep register pipeline. ----
__global__ __launch_bounds__(256) void k_gemm(const uint* __restrict__ Apf,
                                              const ushort* __restrict__ Xthf,
                                              const ushort* __restrict__ Xtlf,
                                              float* __restrict__ Yp,
                                              int kcw) {
  int b = blockIdx.x;
  int mt = b & 31, sk = b >> 5;
  int rbase = mt << 7;
  int kt0 = (sk * kcw) >> 4;
  int nks = kcw >> 4;

  int t = threadIdx.x, lane = t & 63, wid = t >> 6;
  int wm = wid >> 1, wn = wid & 1;
  int l31 = lane & 31, lh = lane >> 5;

  int m0 = rbase + wm * 64 + l31;
  int c0 = wn * 64 + l31;

  const uint*   pa  = Apf  + ((size_t)kt0 * 4096 + m0) * 16 + lh * 8;
  const ushort* pbh = Xthf + ((size_t)kt0 * 128 + c0) * 16 + lh * 8;
  const ushort* pbl = Xtlf + ((size_t)kt0 * 128 + c0) * 16 + lh * 8;

  f32x16 acc[2][2];
#pragma unroll
  for (int mi = 0; mi < 2; mi++)
#pragma unroll
    for (int ni = 0; ni < 2; ni++)
#pragma unroll
      for (int r = 0; r < 16; r++) acc[mi][ni][r] = 0.f;

#define LOADK(KS, A00, A01, A10, A11, BH0, BL0, BH1, BL1) {                    \
    const uint* ap_ = pa + (size_t)(KS) * 65536;                               \
    A00 = *(const u32x4*)(ap_);                                                \
    A01 = *(const u32x4*)(ap_ + 4);                                            \
    A10 = *(const u32x4*)(ap_ + 512);                                          \
    A11 = *(const u32x4*)(ap_ + 516);                                          \
    const ushort* bh_ = pbh + (size_t)(KS) * 2048;                             \
    const ushort* bl_ = pbl + (size_t)(KS) * 2048;                             \
    BH0 = *(const short8*)(bh_);                                               \
    BH1 = *(const short8*)(bh_ + 512);                                         \
    BL0 = *(const short8*)(bl_);                                               \
    BL1 = *(const short8*)(bl_ + 512);                                         \
  }

#define COMPUTE(A00, A01, A10, A11, BH0, BL0, BH1, BL1) {                      \
    short8 ah, al;                                                             \
    unpack8(A00, A01, ah, al);                                                 \
    acc[0][0] = __builtin_amdgcn_mfma_f32_32x32x16_bf16(ah, BH0, acc[0][0], 0, 0, 0); \
    acc[0][0] = __builtin_amdgcn_mfma_f32_32x32x16_bf16(ah, BL0, acc[0][0], 0, 0, 0); \
    acc[0][0] = __builtin_amdgcn_mfma_f32_32x32x16_bf16(al, BH0, acc[0][0], 0, 0, 0); \
    acc[0][1] = __builtin_amdgcn_mfma_f32_32x32x16_bf16(ah, BH1, acc[0][1], 0, 0, 0); \
    acc[0][1] = __builtin_amdgcn_mfma_f32_32x32x16_bf16(ah, BL1, acc[0][1], 0, 0, 0); \
    acc[0][1] = __builtin_amdgcn_mfma_f32_32x32x16_bf16(al, BH1, acc[0][1], 0, 0, 0); \
    unpack8(A10, A11, ah, al);                                                 \
    acc[1][0] = __builtin_amdgcn_mfma_f32_32x32x16_bf16(ah, BH0, acc[1][0], 0, 0, 0); \
    acc[1][0] = __builtin_amdgcn_mfma_f32_32x32x16_bf16(ah, BL0, acc[1][0], 0, 0, 0); \
    acc[1][0] = __builtin_amdgcn_mfma_f32_32x32x16_bf16(al, BH0, acc[1][0], 0, 0, 0); \
    acc[1][1] = __builtin_amdgcn_mfma_f32_32x32x16_bf16(ah, BH1, acc[1][1], 0, 0, 0); \
    acc[1][1] = __builtin_amdgcn_mfma_f32_32x32x16_bf16(ah, BL1, acc[1][1], 0, 0, 0); \
    acc[1][1] = __builtin_amdgcn_mfma_f32_32x32x16_bf16(al, BH1, acc[1][1], 0, 0, 0); \
  }

  u32x4 a00A, a01A, a10A, a11A, a00B, a01B, a10B, a11B;
  short8 bh0A, bl0A, bh1A, bl1A, bh0B, bl0B, bh1B, bl1B;

  LOADK(0, a00A, a01A, a10A, a11A, bh0A, bl0A, bh1A, bl1A);
  for (int ks = 0; ks < nks; ks += 2) {
    LOADK(ks + 1, a00B, a01B, a10B, a11B, bh0B, bl0B, bh1B, bl1B);
    COMPUTE(a00A, a01A, a10A, a11A, bh0A, bl0A, bh1A, bl1A);
    if (ks + 2 < nks) LOADK(ks + 2, a00A, a01A, a10A, a11A, bh0A, bl0A, bh1A, bl1A);
    COMPUTE(a00B, a01B, a10B, a11B, bh0B, bl0B, bh1B, bl1B);
  }

  float* yb = Yp + (size_t)sk * (BSZ * NCP);
#pragma unroll
  for (int mi = 0; mi < 2; mi++)
#pragma unroll
    for (int ni = 0; ni < 2; ni++)
#pragma unroll
      for (int r = 0; r < 16; r++) {
        int row = rbase + wm * 64 + mi * 32 + (r & 3) + 8 * (r >> 2) + 4 * lh;
        int col = wn * 64 + ni * 32 + l31;
        yb[(size_t)row * NCP + col] = acc[mi][ni][r];
      }
}

// ---- epilogue: sum partials, div, entropy, X+=div, outputs, X split (frag-major) ----
__global__ __launch_bounds__(256) void k_epilogue2(const float* __restrict__ Yp,
                                                   float* __restrict__ X,
                                                   float* __restrict__ out,
                                                   ushort* __restrict__ Xthf,
                                                   ushort* __restrict__ Xtlf,
                                                   int tit, int skn) {
  __shared__ float xn[16][132];
  int t = threadIdx.x;
  int lane = t & 63, w = t >> 6;
  int r0 = blockIdx.x * 16;
  int c0 = lane << 1;
#pragma unroll
  for (int rr = 0; rr < 4; rr++) {
    int row = r0 + w * 4 + rr;
    float y0 = 0.f, y1 = 0.f;
    for (int sk = 0; sk < skn; sk++) {
      float2 v = *(const float2*)(Yp + (size_t)sk * BSZ * NCP + (size_t)row * NCP + c0);
      y0 += v.x; y1 += v.y;
    }
    float2 xv = *(float2*)(X + (size_t)row * NCP + c0);
    float n0 = xv.x * y0, n1 = xv.y * y1;
    float s = wave_sum(n0 + n1);
    float inv = 1.0f / (s + 1e-8f);
    float d0 = n0 * inv, d1 = n1 * inv;
    float e = -(d0 * logf(d0 + 1e-20f)) - (d1 * logf(d1 + 1e-20f));
    e = wave_sum(e);
    float nx0 = xv.x + d0, nx1 = xv.y + d1;
    xv.x = nx0; xv.y = nx1;
    *(float2*)(X + (size_t)row * NCP + c0) = xv;
    xn[w * 4 + rr][c0] = nx0;
    xn[w * 4 + rr][c0 + 1] = nx1;
    if (c0 < NC)     out[((size_t)row * NC + c0) * TIT + tit] = d0;
    if (c0 + 1 < NC) out[((size_t)row * NC + c0 + 1) * TIT + tit] = d1;
    if (lane == 0)   out[(size_t)BSZ * NC * TIT + (size_t)row * TIT + tit] = e;
  }
  __syncthreads();
  // fragment-major write of the 16 new k-rows (kt = r0>>4, sub = half*8+j)
  int n = t & 127, half = t >> 7;
  ushort hh[8], ll[8];
#pragma unroll
  for (int j = 0; j < 8; j++) {
    float v = xn[half * 8 + j][n];
    ushort hi = f2bf(v);
    hh[j] = hi;
    ll[j] = f2bf(v - bf2f(hi));
  }
  size_t bofs = ((size_t)(r0 >> 4) * NCP + n) * 16 + half * 8;
  uint4 oh, ol;
  oh.x = (uint)hh[0] | ((uint)hh[1] << 16);
  oh.y = (uint)hh[2] | ((uint)hh[3] << 16);
  oh.z = (uint)hh[4] | ((uint)hh[5] << 16);
  oh.w = (uint)hh[6] | ((uint)hh[7] << 16);
  ol.x = (uint)ll[0] | ((uint)ll[1] << 16);
  ol.y = (uint)ll[2] | ((uint)ll[3] << 16);
  ol.z = (uint)ll[4] | ((uint)ll[5] << 16);
  ol.w = (uint)ll[6] | ((uint)ll[7] << 16);
  *(uint4*)(Xthf + bofs) = oh;
  *(uint4*)(Xtlf + bofs) = ol;
}

extern "C" void kernel_launch(void* const* d_in, const int* in_sizes, int n_in,
                              void* d_out, int out_size, void* d_ws, size_t ws_size,
                              hipStream_t stream) {
  const float* emb = (const float*)d_in[0];
  const int* lab = (const int*)d_in[1];
  float* out = (float*)d_out;
  float* ws = (float*)d_ws;

  uint*   nep  = (uint*)ws;                      // region0, dead after syrk
  float*  X    = ws;                             // aliases nep (post-syrk)
  ushort* Xthf = (ushort*)(ws + 524288);
  ushort* Xtlf = (ushort*)(ws + 524288 + 262144);
  float*  A    = ws + 4194304;                   // fragment-major fp32 -> packed
  uint*   Apf  = (uint*)A;
  float*  Yp   = ws + 20971520;

  size_t need16 = ((size_t)20971520 + 16 * 524288 + 16) * 4;
  int skn = (ws_size >= need16) ? 16 : 8;
  int kcw = BSZ / skn;

  float* misc = ws + 20971520 + (size_t)skn * 524288;
  double* macc = (double*)misc;
  float* meanf = misc + 2;
  int* flag = (int*)(misc + 3);

  k_detect<<<dim3(1), dim3(256), 0, stream>>>(lab, macc, flag);
  k_normalize<<<dim3(BSZ), dim3(256), 0, stream>>>(emb, nep);
  k_syrk<<<dim3(528), dim3(256), 0, stream>>>(nep, A, macc);
  k_meanfin<<<dim3(1), dim3(1), 0, stream>>>(macc, meanf);
  k_split_a<<<dim3(4096), dim3(256), 0, stream>>>(A, meanf);
  k_init_x<<<dim3((BSZ * (NCP / 4) + 255) / 256), dim3(256), 0, stream>>>(lab, flag, X);
  k_splitx0<<<dim3(128), dim3(256), 0, stream>>>(X, Xthf, Xtlf);
  for (int t = 0; t < TIT; t++) {
    k_gemm<<<dim3(32 * skn), dim3(256), 0, stream>>>(Apf, Xthf, Xtlf, Yp, kcw);
    k_epilogue2<<<dim3(256), dim3(256), 0, stream>>>(Yp, X, out, Xthf, Xtlf, t, skn);
  }
}

// Round 6
// 1198.652 us; speedup vs baseline: 1.4574x; 1.2366x over previous
//
#include <hip/hip_runtime.h>
#include <math.h>

// GTG replicator dynamics. Round 6: 4-deep register pipeline in the no-LDS
// fragment-major GEMM (covers L3 latency); 1024-thread epilogue (4 waves/SIMD)
// for the split-K gather. Split-bf16 3-product MFMA (~fp32) everywhere.
//
// Layouts:
//   Apf  [kt=256][m=4096][sub=16] packed (hi16|lo16) fragment-major.
//   Xthf/Xtlf [kt=256][n=128][sub=16] bf16 fragment-major.
//
// ws layout (floats):
//   region0 @ 0: X [4096][128] f32 @ 0; Xthf @ 524288; Xtlf @ 786432
//   A    [kt][m][sub] @ 4194304  (67 MB)
//   Yp   [skn][4096][128] @ 20971520
//   misc @ 20971520 + skn*524288

#define BSZ  4096
#define DIM  1024
#define NC   100
#define NCP  128
#define NLAB 2048
#define TIT  30

typedef short short8 __attribute__((ext_vector_type(8)));
typedef float f32x16 __attribute__((ext_vector_type(16)));
typedef uint  u32x4  __attribute__((ext_vector_type(4)));

__device__ __forceinline__ float wave_sum(float v) {
#pragma unroll
  for (int off = 32; off > 0; off >>= 1) v += __shfl_xor(v, off, 64);
  return v;
}

__device__ __forceinline__ ushort f2bf(float f) {  // RN float->bf16 bits
  uint u = __float_as_uint(f);
  return (ushort)((u + 0x7fffu + ((u >> 16) & 1u)) >> 16);
}
__device__ __forceinline__ float bf2f(ushort h) {
  return __uint_as_float(((uint)h) << 16);
}
__device__ __forceinline__ uint packsplit(float a) {
  ushort hi = f2bf(a);
  ushort lo = f2bf(a - bf2f(hi));
  return ((uint)hi << 16) | (uint)lo;
}

__device__ __forceinline__ void glds16(const void* g, void* l) {
  __builtin_amdgcn_global_load_lds((const __attribute__((address_space(1))) void*)g,
                                   (__attribute__((address_space(3))) void*)l, 16, 0, 0);
}

// unpack 8 packed uints (2x u32x4, k-ascending) -> hi-frag / lo-frag
__device__ __forceinline__ void unpack8(u32x4 u0, u32x4 u1, short8& h, short8& l) {
  u32x4 hw, lw;
  hw.x = __builtin_amdgcn_perm(u0.y, u0.x, 0x07060302u);
  hw.y = __builtin_amdgcn_perm(u0.w, u0.z, 0x07060302u);
  hw.z = __builtin_amdgcn_perm(u1.y, u1.x, 0x07060302u);
  hw.w = __builtin_amdgcn_perm(u1.w, u1.z, 0x07060302u);
  lw.x = __builtin_amdgcn_perm(u0.y, u0.x, 0x05040100u);
  lw.y = __builtin_amdgcn_perm(u0.w, u0.z, 0x05040100u);
  lw.z = __builtin_amdgcn_perm(u1.y, u1.x, 0x05040100u);
  lw.w = __builtin_amdgcn_perm(u1.w, u1.z, 0x05040100u);
  h = __builtin_bit_cast(short8, hw);
  l = __builtin_bit_cast(short8, lw);
}

// ---- detect label dtype (int32 vs int64 layout) + zero mean acc ----
__global__ void k_detect(const int* __restrict__ lab, double* macc, int* flag) {
  __shared__ int bad;
  if (threadIdx.x == 0) bad = 0;
  __syncthreads();
  int my = 0;
  for (int i = threadIdx.x; i < 1024; i += 256) {
    int lo = lab[2 * i], hi = lab[2 * i + 1];
    if (hi != 0 || lo < 0 || lo >= NC) my = 1;
  }
  if (my) bad = 1;
  __syncthreads();
  if (threadIdx.x == 0) { *macc = 0.0; *flag = (bad ? 0 : 1); }
}

// ---- X0 ----
__global__ void k_init_x(const int* __restrict__ lab, const int* __restrict__ flag,
                         float* __restrict__ X) {
  int gid = blockIdx.x * 256 + threadIdx.x;
  if (gid >= BSZ * (NCP / 4)) return;
  int i = gid >> 5, c4 = (gid & 31) << 2;
  float4 v;
  if (i < NLAB) {
    int l = (*flag) ? lab[2 * i] : lab[i];
    v.x = (c4 + 0 == l) ? 1.f : 0.f;
    v.y = (c4 + 1 == l) ? 1.f : 0.f;
    v.z = (c4 + 2 == l) ? 1.f : 0.f;
    v.w = (c4 + 3 == l) ? 1.f : 0.f;
  } else {
    v.x = (c4 + 0 < NC) ? 0.01f : 0.f;
    v.y = (c4 + 1 < NC) ? 0.01f : 0.f;
    v.z = (c4 + 2 < NC) ? 0.01f : 0.f;
    v.w = (c4 + 3 < NC) ? 0.01f : 0.f;
  }
  *(float4*)(X + (size_t)i * NCP + c4) = v;
}

// ---- row-normalize embedding -> packed split-bf16 ne ----
__global__ __launch_bounds__(256) void k_normalize(const float* __restrict__ emb,
                                                   uint* __restrict__ nep) {
  int row = blockIdx.x, t = threadIdx.x;
  float4 v = ((const float4*)(emb + (size_t)row * DIM))[t];
  float ss = v.x * v.x + v.y * v.y + v.z * v.z + v.w * v.w;
  ss = wave_sum(ss);
  __shared__ float red[4];
  int lane = t & 63, wid = t >> 6;
  if (lane == 0) red[wid] = ss;
  __syncthreads();
  float tot = red[0] + red[1] + red[2] + red[3];
  float sc = 1.0f / (sqrtf(tot) + 1e-12f);
  uint4 o;
  o.x = packsplit(v.x * sc);
  o.y = packsplit(v.y * sc);
  o.z = packsplit(v.z * sc);
  o.w = packsplit(v.w * sc);
  ((uint4*)(nep + (size_t)row * DIM))[t] = o;
}

// ---- A = ne*ne^T via split-bf16 MFMA; clamp[0,1], diag=0, mean acc.
// Stores fragment-major fp32: Af[kt=gc>>4][m=gr][sub=gc&15]. ----
__global__ __launch_bounds__(256) void k_syrk(const uint* __restrict__ nep,
                                              float* __restrict__ Af,
                                              double* __restrict__ macc) {
  int p = blockIdx.x;
  int bi = 0, rem = p;
  while (rem >= 32 - bi) { rem -= 32 - bi; bi++; }
  int bj = bi + rem;
  int rb = bi << 7, cb = bj << 7;

  __shared__ uint sP[2][2][4096];
  __shared__ float red[4];

  int t = threadIdx.x, lane = t & 63, wid = t >> 6;
  int wm = wid >> 1, wn = wid & 1;
  int l31 = lane & 31, lh = lane >> 5;

  f32x16 acc[2][2];
#pragma unroll
  for (int mi = 0; mi < 2; mi++)
#pragma unroll
    for (int ni = 0; ni < 2; ni++)
#pragma unroll
      for (int r = 0; r < 16; r++) acc[mi][ni][r] = 0.f;

#define SYRK_STAGE(BUF, K0) {                                                  \
    int base0 = rb, base1 = cb;                                                \
    _Pragma("unroll")                                                          \
    for (int i = 0; i < 4; i++) {                                              \
      int s = wid * 256 + i * 64 + lane;                                       \
      int row = s >> 3;                                                        \
      int g = (s & 7) ^ (row & 7);                                             \
      glds16(nep + (size_t)(base0 + row) * DIM + (K0) + g * 4,                 \
             &sP[BUF][0][(wid * 256 + i * 64) * 4]);                           \
      glds16(nep + (size_t)(base1 + row) * DIM + (K0) + g * 4,                 \
             &sP[BUF][1][(wid * 256 + i * 64) * 4]);                           \
    }                                                                          \
  }

  SYRK_STAGE(0, 0);
  __syncthreads();
  for (int kt = 0; kt < 32; kt++) {
    int cur = kt & 1;
    if (kt + 1 < 32) SYRK_STAGE(cur ^ 1, (kt + 1) * 32);
#pragma unroll
    for (int ks = 0; ks < 2; ks++) {
      int g0 = ks * 4 + lh * 2;
      short8 ah[2], al[2], bh[2], bl[2];
#pragma unroll
      for (int mi = 0; mi < 2; mi++) {
        int row = wm * 64 + mi * 32 + l31;
        const uint* pb = &sP[cur][0][0];
        u32x4 u0 = *(const u32x4*)(pb + ((row << 3) + (g0 ^ (row & 7))) * 4);
        u32x4 u1 = *(const u32x4*)(pb + ((row << 3) + ((g0 + 1) ^ (row & 7))) * 4);
        unpack8(u0, u1, ah[mi], al[mi]);
      }
#pragma unroll
      for (int ni = 0; ni < 2; ni++) {
        int row = wn * 64 + ni * 32 + l31;
        const uint* pb = &sP[cur][1][0];
        u32x4 u0 = *(const u32x4*)(pb + ((row << 3) + (g0 ^ (row & 7))) * 4);
        u32x4 u1 = *(const u32x4*)(pb + ((row << 3) + ((g0 + 1) ^ (row & 7))) * 4);
        unpack8(u0, u1, bh[ni], bl[ni]);
      }
#pragma unroll
      for (int mi = 0; mi < 2; mi++)
#pragma unroll
        for (int ni = 0; ni < 2; ni++) {
          acc[mi][ni] = __builtin_amdgcn_mfma_f32_32x32x16_bf16(ah[mi], bh[ni], acc[mi][ni], 0, 0, 0);
          acc[mi][ni] = __builtin_amdgcn_mfma_f32_32x32x16_bf16(ah[mi], bl[ni], acc[mi][ni], 0, 0, 0);
          acc[mi][ni] = __builtin_amdgcn_mfma_f32_32x32x16_bf16(al[mi], bh[ni], acc[mi][ni], 0, 0, 0);
        }
    }
    __syncthreads();
  }

  // epilogue: clamp, diag, mean; direct fragment-major store (upper tile)
  float lsum = 0.f;
#pragma unroll
  for (int mi = 0; mi < 2; mi++)
#pragma unroll
    for (int ni = 0; ni < 2; ni++)
#pragma unroll
      for (int r = 0; r < 16; r++) {
        int gr = rb + wm * 64 + mi * 32 + (r & 3) + 8 * (r >> 2) + 4 * lh;
        int gc = cb + wn * 64 + ni * 32 + l31;
        float v = acc[mi][ni][r];
        v = fminf(fmaxf(v, 0.f), 1.f);
        if (gr == gc) v = 0.f;
        acc[mi][ni][r] = v;
        lsum += v;
        Af[(size_t)(gc >> 4) * 65536 + ((size_t)gr << 4) + (gc & 15)] = v;
      }
  if (bi != bj) lsum *= 2.f;
  float bs = wave_sum(lsum);
  if (lane == 0) red[wid] = bs;
  __syncthreads();
  if (t == 0) atomicAdd(macc, (double)(red[0] + red[1] + red[2] + red[3]));

  // mirror store A[gc][gr] via LDS transpose, fragment-major addressing
  if (bi != bj) {
    float* tb = (float*)&sP[0][0][0];
#pragma unroll
    for (int ph2 = 0; ph2 < 2; ph2++) {
      __syncthreads();
      if (wm == ph2) {
#pragma unroll
        for (int mi = 0; mi < 2; mi++)
#pragma unroll
          for (int ni = 0; ni < 2; ni++)
#pragma unroll
            for (int r = 0; r < 16; r++) {
              int rl = mi * 32 + (r & 3) + 8 * (r >> 2) + 4 * lh;
              int cl = wn * 64 + ni * 32 + l31;
              tb[rl * 132 + cl] = acc[mi][ni][r];
            }
      }
      __syncthreads();
      int col = t >> 1, rh = (t & 1) * 32;
      int grbase = rb + ph2 * 64 + rh;
#pragma unroll
      for (int q = 0; q < 8; q++) {
        int g4 = grbase + q * 4;
        float4 v4 = make_float4(tb[(rh + q * 4 + 0) * 132 + col],
                                tb[(rh + q * 4 + 1) * 132 + col],
                                tb[(rh + q * 4 + 2) * 132 + col],
                                tb[(rh + q * 4 + 3) * 132 + col]);
        *(float4*)(Af + (size_t)(g4 >> 4) * 65536 + ((size_t)(cb + col) << 4) + (g4 & 15)) = v4;
      }
    }
  }
}

__global__ void k_meanfin(const double* __restrict__ macc, float* __restrict__ meanf) {
  *meanf = (float)(*macc / (double)((long long)BSZ * BSZ));
}

// ---- threshold + split-bf16 + pack, elementwise IN PLACE (layout unchanged) ----
__global__ __launch_bounds__(256) void k_split_a(float* __restrict__ A,
                                                 const float* __restrict__ meanf) {
  float mean = *meanf;
  size_t base = ((size_t)blockIdx.x * 256 + threadIdx.x) * 16;
#pragma unroll
  for (int q = 0; q < 4; q++) {
    float4 v = *(const float4*)(A + base + q * 4);
    uint4 o;
    o.x = packsplit((v.x < mean) ? 0.f : v.x);
    o.y = packsplit((v.y < mean) ? 0.f : v.y);
    o.z = packsplit((v.z < mean) ? 0.f : v.z);
    o.w = packsplit((v.w < mean) ? 0.f : v.w);
    *(uint4*)(A + base + q * 4) = o;
  }
}

// ---- initial X split -> fragment-major Xthf/Xtlf [kt][n][sub] ----
__global__ __launch_bounds__(256) void k_splitx0(const float* __restrict__ X,
                                                 ushort* __restrict__ Xthf,
                                                 ushort* __restrict__ Xtlf) {
  int gid = blockIdx.x * 256 + threadIdx.x;
  int n = gid & 127, kt = gid >> 7;
  ushort hh[16], ll[16];
#pragma unroll
  for (int j = 0; j < 16; j++) {
    float v = X[(size_t)(kt * 16 + j) * NCP + n];
    ushort hi = f2bf(v);
    hh[j] = hi;
    ll[j] = f2bf(v - bf2f(hi));
  }
  size_t base = ((size_t)kt * NCP + n) * 16;
#pragma unroll
  for (int g = 0; g < 2; g++) {
    uint4 oh, ol;
    oh.x = (uint)hh[g*8+0] | ((uint)hh[g*8+1] << 16);
    oh.y = (uint)hh[g*8+2] | ((uint)hh[g*8+3] << 16);
    oh.z = (uint)hh[g*8+4] | ((uint)hh[g*8+5] << 16);
    oh.w = (uint)hh[g*8+6] | ((uint)hh[g*8+7] << 16);
    ol.x = (uint)ll[g*8+0] | ((uint)ll[g*8+1] << 16);
    ol.y = (uint)ll[g*8+2] | ((uint)ll[g*8+3] << 16);
    ol.z = (uint)ll[g*8+4] | ((uint)ll[g*8+5] << 16);
    ol.w = (uint)ll[g*8+6] | ((uint)ll[g*8+7] << 16);
    *(uint4*)(Xthf + base + g * 8) = oh;
    *(uint4*)(Xtlf + base + g * 8) = ol;
  }
}

// ---- MFMA GEMM, fragment-major direct-global loads, 4-deep register
// pipeline (prefetch 3 k-steps ahead covers L3 latency). No LDS/barriers. ----
__global__ __launch_bounds__(256) void k_gemm(const uint* __restrict__ Apf,
                                              const ushort* __restrict__ Xthf,
                                              const ushort* __restrict__ Xtlf,
                                              float* __restrict__ Yp,
                                              int kcw) {
  int b = blockIdx.x;
  int mt = b & 31, sk = b >> 5;
  int rbase = mt << 7;
  int kt0 = (sk * kcw) >> 4;
  int nks = kcw >> 4;

  int t = threadIdx.x, lane = t & 63, wid = t >> 6;
  int wm = wid >> 1, wn = wid & 1;
  int l31 = lane & 31, lh = lane >> 5;

  int m0 = rbase + wm * 64 + l31;
  int c0 = wn * 64 + l31;

  const uint*   pa  = Apf  + ((size_t)kt0 * 4096 + m0) * 16 + lh * 8;
  const ushort* pbh = Xthf + ((size_t)kt0 * 128 + c0) * 16 + lh * 8;
  const ushort* pbl = Xtlf + ((size_t)kt0 * 128 + c0) * 16 + lh * 8;

  f32x16 acc[2][2];
#pragma unroll
  for (int mi = 0; mi < 2; mi++)
#pragma unroll
    for (int ni = 0; ni < 2; ni++)
#pragma unroll
      for (int r = 0; r < 16; r++) acc[mi][ni][r] = 0.f;

#define DECLP(S) u32x4 a00##S, a01##S, a10##S, a11##S;                         \
                 short8 bh0##S, bl0##S, bh1##S, bl1##S;

#define LOADK(KS, S) {                                                         \
    const uint* ap_ = pa + (size_t)(KS) * 65536;                               \
    a00##S = *(const u32x4*)(ap_);                                             \
    a01##S = *(const u32x4*)(ap_ + 4);                                         \
    a10##S = *(const u32x4*)(ap_ + 512);                                       \
    a11##S = *(const u32x4*)(ap_ + 516);                                       \
    const ushort* bh_ = pbh + (size_t)(KS) * 2048;                             \
    const ushort* bl_ = pbl + (size_t)(KS) * 2048;                             \
    bh0##S = *(const short8*)(bh_);                                            \
    bh1##S = *(const short8*)(bh_ + 512);                                      \
    bl0##S = *(const short8*)(bl_);                                            \
    bl1##S = *(const short8*)(bl_ + 512);                                      \
  }

#define COMPUTE(S) {                                                           \
    short8 ah, al;                                                             \
    unpack8(a00##S, a01##S, ah, al);                                           \
    acc[0][0] = __builtin_amdgcn_mfma_f32_32x32x16_bf16(ah, bh0##S, acc[0][0], 0, 0, 0); \
    acc[0][0] = __builtin_amdgcn_mfma_f32_32x32x16_bf16(ah, bl0##S, acc[0][0], 0, 0, 0); \
    acc[0][0] = __builtin_amdgcn_mfma_f32_32x32x16_bf16(al, bh0##S, acc[0][0], 0, 0, 0); \
    acc[0][1] = __builtin_amdgcn_mfma_f32_32x32x16_bf16(ah, bh1##S, acc[0][1], 0, 0, 0); \
    acc[0][1] = __builtin_amdgcn_mfma_f32_32x32x16_bf16(ah, bl1##S, acc[0][1], 0, 0, 0); \
    acc[0][1] = __builtin_amdgcn_mfma_f32_32x32x16_bf16(al, bh1##S, acc[0][1], 0, 0, 0); \
    unpack8(a10##S, a11##S, ah, al);                                           \
    acc[1][0] = __builtin_amdgcn_mfma_f32_32x32x16_bf16(ah, bh0##S, acc[1][0], 0, 0, 0); \
    acc[1][0] = __builtin_amdgcn_mfma_f32_32x32x16_bf16(ah, bl0##S, acc[1][0], 0, 0, 0); \
    acc[1][0] = __builtin_amdgcn_mfma_f32_32x32x16_bf16(al, bh0##S, acc[1][0], 0, 0, 0); \
    acc[1][1] = __builtin_amdgcn_mfma_f32_32x32x16_bf16(ah, bh1##S, acc[1][1], 0, 0, 0); \
    acc[1][1] = __builtin_amdgcn_mfma_f32_32x32x16_bf16(ah, bl1##S, acc[1][1], 0, 0, 0); \
    acc[1][1] = __builtin_amdgcn_mfma_f32_32x32x16_bf16(al, bh1##S, acc[1][1], 0, 0, 0); \
  }

  DECLP(A) DECLP(B) DECLP(C) DECLP(D)

  LOADK(0, A);
  LOADK(1, B);
  LOADK(2, C);
  for (int ks = 0; ks < nks; ks += 4) {
    if (ks + 3 < nks) LOADK(ks + 3, D);
    COMPUTE(A);
    if (ks + 4 < nks) LOADK(ks + 4, A);
    COMPUTE(B);
    if (ks + 5 < nks) LOADK(ks + 5, B);
    COMPUTE(C);
    if (ks + 6 < nks) LOADK(ks + 6, C);
    COMPUTE(D);
  }

  float* yb = Yp + (size_t)sk * (BSZ * NCP);
#pragma unroll
  for (int mi = 0; mi < 2; mi++)
#pragma unroll
    for (int ni = 0; ni < 2; ni++)
#pragma unroll
      for (int r = 0; r < 16; r++) {
        int row = rbase + wm * 64 + mi * 32 + (r & 3) + 8 * (r >> 2) + 4 * lh;
        int col = wn * 64 + ni * 32 + l31;
        yb[(size_t)row * NCP + col] = acc[mi][ni][r];
      }
}

// ---- epilogue: one wave per row (16 rows/block, 1024 thr -> 4 waves/SIMD):
// sum partials, div, entropy, X+=div, outputs, X split (frag-major) ----
__global__ __launch_bounds__(1024) void k_epilogue2(const float* __restrict__ Yp,
                                                    float* __restrict__ X,
                                                    float* __restrict__ out,
                                                    ushort* __restrict__ Xthf,
                                                    ushort* __restrict__ Xtlf,
                                                    int tit, int skn) {
  __shared__ float xn[16][132];
  int t = threadIdx.x;
  int lane = t & 63, w = t >> 6;       // w = 0..15: row within block
  int r0 = blockIdx.x * 16;
  int c0 = lane << 1;
  int row = r0 + w;
  float y0 = 0.f, y1 = 0.f;
  for (int sk = 0; sk < skn; sk++) {
    float2 v = *(const float2*)(Yp + (size_t)sk * BSZ * NCP + (size_t)row * NCP + c0);
    y0 += v.x; y1 += v.y;
  }
  float2 xv = *(float2*)(X + (size_t)row * NCP + c0);
  float n0 = xv.x * y0, n1 = xv.y * y1;
  float s = wave_sum(n0 + n1);
  float inv = 1.0f / (s + 1e-8f);
  float d0 = n0 * inv, d1 = n1 * inv;
  float e = -(d0 * logf(d0 + 1e-20f)) - (d1 * logf(d1 + 1e-20f));
  e = wave_sum(e);
  float nx0 = xv.x + d0, nx1 = xv.y + d1;
  xv.x = nx0; xv.y = nx1;
  *(float2*)(X + (size_t)row * NCP + c0) = xv;
  xn[w][c0] = nx0;
  xn[w][c0 + 1] = nx1;
  if (c0 < NC)     out[((size_t)row * NC + c0) * TIT + tit] = d0;
  if (c0 + 1 < NC) out[((size_t)row * NC + c0 + 1) * TIT + tit] = d1;
  if (lane == 0)   out[(size_t)BSZ * NC * TIT + (size_t)row * TIT + tit] = e;
  __syncthreads();
  // fragment-major write: kt = r0>>4; thread handles (n, sub pair jj*2..+1)
  int n = t & 127, jj = t >> 7;        // jj = 0..7
  float v0 = xn[jj * 2][n], v1 = xn[jj * 2 + 1][n];
  ushort h0 = f2bf(v0), l0 = f2bf(v0 - bf2f(h0));
  ushort h1 = f2bf(v1), l1 = f2bf(v1 - bf2f(h1));
  size_t bo = ((size_t)(r0 >> 4) * NCP + n) * 16 + jj * 2;
  *(uint*)(Xthf + bo) = (uint)h0 | ((uint)h1 << 16);
  *(uint*)(Xtlf + bo) = (uint)l0 | ((uint)l1 << 16);
}

extern "C" void kernel_launch(void* const* d_in, const int* in_sizes, int n_in,
                              void* d_out, int out_size, void* d_ws, size_t ws_size,
                              hipStream_t stream) {
  const float* emb = (const float*)d_in[0];
  const int* lab = (const int*)d_in[1];
  float* out = (float*)d_out;
  float* ws = (float*)d_ws;

  uint*   nep  = (uint*)ws;                      // region0, dead after syrk
  float*  X    = ws;                             // aliases nep (post-syrk)
  ushort* Xthf = (ushort*)(ws + 524288);
  ushort* Xtlf = (ushort*)(ws + 524288 + 262144);
  float*  A    = ws + 4194304;                   // fragment-major fp32 -> packed
  uint*   Apf  = (uint*)A;
  float*  Yp   = ws + 20971520;

  size_t need16 = ((size_t)20971520 + 16 * 524288 + 16) * 4;
  int skn = (ws_size >= need16) ? 16 : 8;
  int kcw = BSZ / skn;

  float* misc = ws + 20971520 + (size_t)skn * 524288;
  double* macc = (double*)misc;
  float* meanf = misc + 2;
  int* flag = (int*)(misc + 3);

  k_detect<<<dim3(1), dim3(256), 0, stream>>>(lab, macc, flag);
  k_normalize<<<dim3(BSZ), dim3(256), 0, stream>>>(emb, nep);
  k_syrk<<<dim3(528), dim3(256), 0, stream>>>(nep, A, macc);
  k_meanfin<<<dim3(1), dim3(1), 0, stream>>>(macc, meanf);
  k_split_a<<<dim3(4096), dim3(256), 0, stream>>>(A, meanf);
  k_init_x<<<dim3((BSZ * (NCP / 4) + 255) / 256), dim3(256), 0, stream>>>(lab, flag, X);
  k_splitx0<<<dim3(128), dim3(256), 0, stream>>>(X, Xthf, Xtlf);
  for (int t = 0; t < TIT; t++) {
    k_gemm<<<dim3(32 * skn), dim3(256), 0, stream>>>(Apf, Xthf, Xtlf, Yp, kcw);
    k_epilogue2<<<dim3(256), dim3(1024), 0, stream>>>(Yp, X, out, Xthf, Xtlf, t, skn);
  }
}